// Round 8
// baseline (252.649 us; speedup 1.0000x reference)
//
#include <hip/hip_runtime.h>
#include <hip/hip_bf16.h>
#include <math.h>

#define NB 4
#define NL 512
#define ND 128
#define KSTR 136  // 128 + 8 bf16 pad -> 272B row stride; 2-way banks (free per m136)

typedef __attribute__((ext_vector_type(8))) short bf16x8;
typedef __attribute__((ext_vector_type(4))) float f32x4;

__device__ __forceinline__ short f2bf(float f) {
  union { float f; unsigned u; } un; un.f = f;
  unsigned r = un.u + 0x7FFFu + ((un.u >> 16) & 1u);  // RNE
  return (short)(r >> 16);
}

// GELU via sigmoid approximation: gelu(h) ~= h * sigmoid(1.702 h).
// Max abs err ~1e-2 (threshold 7.5e-2). ~3 VALU + 2 trans ops.
__device__ __forceinline__ float gelu_fast(float h) {
  const float e = exp2f(h * -2.4554572f);           // exp2(-1.702*1.4427*h)
  return h * __builtin_amdgcn_rcpf(1.0f + e);
}

// one-time weight prep into d_ws
__global__ void unimol_prep(const float* __restrict__ w1, const float* __restrict__ ln_g,
                            const float* __restrict__ ln_b, const float* __restrict__ b1,
                            const int* __restrict__ nodes,
                            short* __restrict__ w1f, float* __restrict__ b1p,
                            float* __restrict__ npad, float* __restrict__ inva) {
  const int tid = threadIdx.x;
  for (int idx = tid; idx < ND * ND; idx += 256) {
    const int k = idx >> 7, n = idx & (ND - 1);
    w1f[n * ND + k] = f2bf(w1[idx] * ln_g[k]);
  }
  if (tid < ND) {
    float s = b1[tid];
    for (int k = 0; k < ND; ++k) s = fmaf(ln_b[k], w1[k * ND + tid], s);
    b1p[tid] = s;
  }
  for (int j = tid; j < NB * NL; j += 256) npad[j] = (nodes[j] != 0) ? 1.0f : 0.0f;
  const int wv = tid >> 6, lane = tid & 63;
  if (wv < NB) {
    float s = 0.f;
    for (int j = lane; j < NL; j += 64) s += (nodes[wv * NL + j] != 0) ? 1.0f : 0.0f;
    #pragma unroll
    for (int m = 1; m <= 32; m <<= 1) s += __shfl_xor(s, m);
    if (lane == 0) inva[wv] = 1.0f / s;
  }
}

// 512 threads = 8 waves; waves 0-3 process row l0 = 2*pair, waves 4-7 row l1 = 2*pair+1.
// The 35KB w1T tile is staged once and shared by both rows.
__global__ __launch_bounds__(512, 2) void unimol_coord_head(
    const float* __restrict__ x, const float* __restrict__ coord,
    const float* __restrict__ w2, const float* __restrict__ b2,
    const short* __restrict__ w1f, const float* __restrict__ b1pw,
    const float* __restrict__ npadw, const float* __restrict__ invw,
    float* __restrict__ out)
{
  __shared__ __align__(16) short w1T[ND * KSTR];  // [n][k] bf16, gamma-folded
  __shared__ float b1p[ND];
  __shared__ float w2s[ND];
  __shared__ float notpad[NL];
  __shared__ float coord_s[NL * 3];
  __shared__ float red[2][16];

  const int blk = blockIdx.x;
  const int bb = blk >> 8;            // 256 blocks per batch
  const int pair = blk & 255;
  const int tid = threadIdx.x;
  const int row = tid >> 8;           // 0 or 1: which l-row this wave group owns
  const int lrow = 2 * pair + row;
  const int ltid = tid & 255;

  // ---- staging (shared by both rows) ----
  for (int t = tid; t < (ND * ND) / 8; t += 512) {   // 2048 x 16B vector copies
    const int r = t >> 4, cg = (t & 15) << 3;
    *reinterpret_cast<bf16x8*>(&w1T[r * KSTR + cg]) =
        *reinterpret_cast<const bf16x8*>(&w1f[r * ND + cg]);
  }
  if (tid < ND) { b1p[tid] = b1pw[tid]; w2s[tid] = w2[tid]; }
  for (int j = tid; j < NL; j += 512) notpad[j] = npadw[bb * NL + j];
  for (int j = tid; j < NL * 3; j += 512) coord_s[j] = coord[bb * (NL * 3) + j];
  __syncthreads();

  const int lane = tid & 63;
  const int wv4 = (tid >> 6) & 3;   // wave index within this row's group of 4
  const int c = lane & 15;          // A-row within tile / D-column within tile
  const int g = lane >> 4;          // k-group
  const bool live = (notpad[lrow] != 0.0f);

  if (live) {
    // loop-invariant epilogue params -> registers (static indexing)
    float b1r[8], w2r[8];
    #pragma unroll
    for (int nt = 0; nt < 8; ++nt) { b1r[nt] = b1p[16 * nt + c]; w2r[nt] = w2s[16 * nt + c]; }
    const float b2c = b2[0] * (1.0f / 16.0f);
    float s0 = 0.f, sx = 0.f, sy = 0.f, sz = 0.f;
    const size_t xbase = (size_t)(bb * NL + lrow) * (NL * ND);

    // row pointer: advances 64 rows per iter
    const float* xr = x + xbase + (size_t)((wv4 << 4) + c) * ND + 8 * g;

    #pragma unroll 2   // compiler-scheduled 2-iter pipeline: overlap t+1 loads with t compute
    for (int it = 0; it < 8; ++it) {
      const int mbase = (it << 6) + (wv4 << 4);
      const float* xp = xr + (size_t)it * (64 * ND);
      f32x4 xv[8];
      #pragma unroll
      for (int ks = 0; ks < 4; ++ks) {
        xv[2 * ks]     = *reinterpret_cast<const f32x4*>(xp + 32 * ks);
        xv[2 * ks + 1] = *reinterpret_cast<const f32x4*>(xp + 32 * ks + 4);
      }
      // LayerNorm stats: 4 lanes (c, g=0..3) share one row -> xor 16, 32
      float sum = 0.f, sq = 0.f;
      #pragma unroll
      for (int q = 0; q < 8; ++q) {
        #pragma unroll
        for (int j = 0; j < 4; ++j) { const float e = xv[q][j]; sum += e; sq = fmaf(e, e, sq); }
      }
      sum += __shfl_xor(sum, 16); sum += __shfl_xor(sum, 32);
      sq  += __shfl_xor(sq, 16);  sq  += __shfl_xor(sq, 32);
      const float mu = sum * (1.0f / ND);
      const float rs = rsqrtf(fmaf(-mu, mu, sq * (1.0f / ND)) + 1e-5f);
      const float nmr = -mu * rs;

      bf16x8 af[4];
      #pragma unroll
      for (int ks = 0; ks < 4; ++ks) {
        union { bf16x8 v; __hip_bfloat162 h[4]; } u;
        float2 t0, t1, t2, t3;
        t0.x = fmaf(xv[2 * ks][0], rs, nmr);     t0.y = fmaf(xv[2 * ks][1], rs, nmr);
        t1.x = fmaf(xv[2 * ks][2], rs, nmr);     t1.y = fmaf(xv[2 * ks][3], rs, nmr);
        t2.x = fmaf(xv[2 * ks + 1][0], rs, nmr); t2.y = fmaf(xv[2 * ks + 1][1], rs, nmr);
        t3.x = fmaf(xv[2 * ks + 1][2], rs, nmr); t3.y = fmaf(xv[2 * ks + 1][3], rs, nmr);
        u.h[0] = __float22bfloat162_rn(t0); u.h[1] = __float22bfloat162_rn(t1);
        u.h[2] = __float22bfloat162_rn(t2); u.h[3] = __float22bfloat162_rn(t3);
        af[ks] = u.v;
      }

      f32x4 acc[8];
      #pragma unroll
      for (int nt = 0; nt < 8; ++nt) acc[nt] = (f32x4){0.f, 0.f, 0.f, 0.f};
      #pragma unroll
      for (int ks = 0; ks < 4; ++ks) {
        const int koff = 8 * g + 32 * ks;
        #pragma unroll
        for (int nt = 0; nt < 8; ++nt) {
          const bf16x8 bf = *reinterpret_cast<const bf16x8*>(&w1T[(16 * nt + c) * KSTR + koff]);
          acc[nt] = __builtin_amdgcn_mfma_f32_16x16x32_bf16(af[ks], bf, acc[nt], 0, 0, 0);
        }
      }

      // epilogue: +b1, fast GELU, dot w2 -- per-lane PARTIAL sums
      float p[4] = {0.f, 0.f, 0.f, 0.f};
      #pragma unroll
      for (int nt = 0; nt < 8; ++nt) {
        #pragma unroll
        for (int i = 0; i < 4; ++i) {
          const float h = acc[nt][i] + b1r[nt];
          p[i] = fmaf(gelu_fast(h), w2r[nt], p[i]);
        }
      }
      #pragma unroll
      for (int i = 0; i < 4; ++i) {
        const int m = mbase + 4 * g + i;        // D-layout row for this lane
        const float a = (p[i] + b2c) * notpad[m];
        s0 += a;
        sx = fmaf(a, coord_s[3 * m + 0], sx);
        sy = fmaf(a, coord_s[3 * m + 1], sy);
        sz = fmaf(a, coord_s[3 * m + 2], sz);
      }
    }

    #pragma unroll
    for (int m = 1; m <= 32; m <<= 1) {
      s0 += __shfl_xor(s0, m); sx += __shfl_xor(sx, m);
      sy += __shfl_xor(sy, m); sz += __shfl_xor(sz, m);
    }
    if (lane == 0) {
      red[row][wv4 * 4 + 0] = s0; red[row][wv4 * 4 + 1] = sx;
      red[row][wv4 * 4 + 2] = sy; red[row][wv4 * 4 + 3] = sz;
    }
  } else if (lane == 0) {  // pad row: zero partials so the final reduce is defined
    red[row][wv4 * 4 + 0] = 0.f; red[row][wv4 * 4 + 1] = 0.f;
    red[row][wv4 * 4 + 2] = 0.f; red[row][wv4 * 4 + 3] = 0.f;
  }
  __syncthreads();

  if (ltid == 0) {   // tid 0 -> row 0, tid 256 -> row 1
    const float cx = coord_s[3 * lrow + 0], cy = coord_s[3 * lrow + 1], cz = coord_s[3 * lrow + 2];
    float* o = out + (bb * NL + lrow) * 3;
    if (live) {
      const float S0 = red[row][0] + red[row][4] + red[row][8] + red[row][12];
      const float SX = red[row][1] + red[row][5] + red[row][9] + red[row][13];
      const float SY = red[row][2] + red[row][6] + red[row][10] + red[row][14];
      const float SZ = red[row][3] + red[row][7] + red[row][11] + red[row][15];
      const float ia = invw[bb];
      o[0] = cx + (SX - S0 * cx) * ia;
      o[1] = cy + (SY - S0 * cy) * ia;
      o[2] = cz + (SZ - S0 * cz) * ia;
    } else {
      o[0] = cx; o[1] = cy; o[2] = cz;
    }
  }
}

extern "C" void kernel_launch(void* const* d_in, const int* in_sizes, int n_in,
                              void* d_out, int out_size, void* d_ws, size_t ws_size,
                              hipStream_t stream) {
  const float* x     = (const float*)d_in[0];
  const float* coord = (const float*)d_in[1];
  const int*   nodes = (const int*)d_in[2];
  const float* ln_g  = (const float*)d_in[3];
  const float* ln_b  = (const float*)d_in[4];
  const float* w1    = (const float*)d_in[5];
  const float* b1    = (const float*)d_in[6];
  const float* w2    = (const float*)d_in[7];
  const float* b2    = (const float*)d_in[8];
  float* out = (float*)d_out;

  short* w1f  = (short*)d_ws;
  float* b1p  = (float*)((char*)d_ws + 32768);
  float* npad = (float*)((char*)d_ws + 33280);
  float* inva = (float*)((char*)d_ws + 41472);
  hipLaunchKernelGGL(unimol_prep, dim3(1), dim3(256), 0, stream,
                     w1, ln_g, ln_b, b1, nodes, w1f, b1p, npad, inva);
  hipLaunchKernelGGL(unimol_coord_head, dim3(NB * NL / 2), dim3(512), 0, stream,
                     x, coord, w2, b2, w1f, b1p, npad, inva, out);
}

// Round 9
// 252.465 us; speedup vs baseline: 1.0007x; 1.0007x over previous
//
#include <hip/hip_runtime.h>
#include <hip/hip_bf16.h>
#include <math.h>

#define NB 4
#define NL 512
#define ND 128
#define KSTR 136  // 272B row stride; b128 reads processed 8 lanes/cy -> disjoint bank quads

typedef __attribute__((ext_vector_type(8))) short bf16x8;
typedef __attribute__((ext_vector_type(4))) float f32x4;

__device__ __forceinline__ short f2bf(float f) {
  union { float f; unsigned u; } un; un.f = f;
  unsigned r = un.u + 0x7FFFu + ((un.u >> 16) & 1u);  // RNE
  return (short)(r >> 16);
}

// GELU via sigmoid approximation: gelu(h) ~= h * sigmoid(1.702 h).
__device__ __forceinline__ float gelu_fast(float h) {
  const float e = exp2f(h * -2.4554572f);
  return h * __builtin_amdgcn_rcpf(1.0f + e);
}

__global__ void unimol_prep(const float* __restrict__ w1, const float* __restrict__ ln_g,
                            const float* __restrict__ ln_b, const float* __restrict__ b1,
                            const int* __restrict__ nodes,
                            short* __restrict__ w1f, float* __restrict__ b1p,
                            float* __restrict__ npad, float* __restrict__ inva) {
  const int tid = threadIdx.x;
  for (int idx = tid; idx < ND * ND; idx += 256) {
    const int k = idx >> 7, n = idx & (ND - 1);
    w1f[n * ND + k] = f2bf(w1[idx] * ln_g[k]);
  }
  if (tid < ND) {
    float s = b1[tid];
    for (int k = 0; k < ND; ++k) s = fmaf(ln_b[k], w1[k * ND + tid], s);
    b1p[tid] = s;
  }
  for (int j = tid; j < NB * NL; j += 256) npad[j] = (nodes[j] != 0) ? 1.0f : 0.0f;
  const int wv = tid >> 6, lane = tid & 63;
  if (wv < NB) {
    float s = 0.f;
    for (int j = lane; j < NL; j += 64) s += (nodes[wv * NL + j] != 0) ? 1.0f : 0.0f;
    #pragma unroll
    for (int m = 1; m <= 32; m <<= 1) s += __shfl_xor(s, m);
    if (lane == 0) inva[wv] = 1.0f / s;
  }
}

// MODE 0: full kernel (r7-identical body), writes `outp`.
// MODE 1: loads + LN only; fabricated accumulation keeps loads/LN live; writes scratch.
template <int MODE>
__global__ __launch_bounds__(512, 2) void unimol_coord_head(
    const float* __restrict__ x, const float* __restrict__ coord,
    const float* __restrict__ w2, const float* __restrict__ b2,
    const short* __restrict__ w1f, const float* __restrict__ b1pw,
    const float* __restrict__ npadw, const float* __restrict__ invw,
    float* __restrict__ outp)
{
  __shared__ __align__(16) short w1T[ND * KSTR];
  __shared__ float b1p[ND];
  __shared__ float w2s[ND];
  __shared__ float notpad[NL];
  __shared__ float coord_s[NL * 3];
  __shared__ float red[2][16];

  const int blk = blockIdx.x;
  const int bb = blk >> 8;
  const int pair = blk & 255;
  const int tid = threadIdx.x;
  const int row = tid >> 8;
  const int lrow = 2 * pair + row;
  const int ltid = tid & 255;

  if (MODE == 0) {
    for (int t = tid; t < (ND * ND) / 8; t += 512) {
      const int r = t >> 4, cg = (t & 15) << 3;
      *reinterpret_cast<bf16x8*>(&w1T[r * KSTR + cg]) =
          *reinterpret_cast<const bf16x8*>(&w1f[r * ND + cg]);
    }
    if (tid < ND) { b1p[tid] = b1pw[tid]; w2s[tid] = w2[tid]; }
  }
  for (int j = tid; j < NL; j += 512) notpad[j] = npadw[bb * NL + j];
  for (int j = tid; j < NL * 3; j += 512) coord_s[j] = coord[bb * (NL * 3) + j];
  __syncthreads();

  const int lane = tid & 63;
  const int wv4 = (tid >> 6) & 3;
  const int c = lane & 15;
  const int g = lane >> 4;
  const bool live = (notpad[lrow] != 0.0f) || (MODE == 1);

  if (live) {
    const float b2c = b2[0] * (1.0f / 16.0f);
    float s0 = 0.f, sx = 0.f, sy = 0.f, sz = 0.f;
    const size_t xbase = (size_t)(bb * NL + lrow) * (NL * ND);
    const float* xr = x + xbase + (size_t)((wv4 << 4) + c) * ND + 8 * g;

    for (int it = 0; it < 8; ++it, xr += 64 * ND) {
      const int mbase = (it << 6) + (wv4 << 4);
      f32x4 xv[8];
      #pragma unroll
      for (int ks = 0; ks < 4; ++ks) {
        xv[2 * ks]     = *reinterpret_cast<const f32x4*>(xr + 32 * ks);
        xv[2 * ks + 1] = *reinterpret_cast<const f32x4*>(xr + 32 * ks + 4);
      }
      float sum = 0.f, sq = 0.f;
      #pragma unroll
      for (int q = 0; q < 8; ++q) {
        #pragma unroll
        for (int j = 0; j < 4; ++j) { const float e = xv[q][j]; sum += e; sq = fmaf(e, e, sq); }
      }
      sum += __shfl_xor(sum, 16); sum += __shfl_xor(sum, 32);
      sq  += __shfl_xor(sq, 16);  sq  += __shfl_xor(sq, 32);
      const float mu = sum * (1.0f / ND);
      const float rs = rsqrtf(fmaf(-mu, mu, sq * (1.0f / ND)) + 1e-5f);
      const float nmr = -mu * rs;

      if (MODE == 1) {
        // probe: consume LN results directly; skip cvt/MFMA/B-reads/gelu
        #pragma unroll
        for (int i = 0; i < 4; ++i) {
          const int m = mbase + 4 * g + i;
          const float a = fmaf(rs, 1e-30f, nmr * 1e-30f) * notpad[m];
          s0 += a;
          sx = fmaf(a, coord_s[3 * m + 0], sx);
          sy = fmaf(a, coord_s[3 * m + 1], sy);
          sz = fmaf(a, coord_s[3 * m + 2], sz);
        }
        continue;
      }

      bf16x8 af[4];
      #pragma unroll
      for (int ks = 0; ks < 4; ++ks) {
        union { bf16x8 v; __hip_bfloat162 h[4]; } u;
        float2 t0, t1, t2, t3;
        t0.x = fmaf(xv[2 * ks][0], rs, nmr);     t0.y = fmaf(xv[2 * ks][1], rs, nmr);
        t1.x = fmaf(xv[2 * ks][2], rs, nmr);     t1.y = fmaf(xv[2 * ks][3], rs, nmr);
        t2.x = fmaf(xv[2 * ks + 1][0], rs, nmr); t2.y = fmaf(xv[2 * ks + 1][1], rs, nmr);
        t3.x = fmaf(xv[2 * ks + 1][2], rs, nmr); t3.y = fmaf(xv[2 * ks + 1][3], rs, nmr);
        u.h[0] = __float22bfloat162_rn(t0); u.h[1] = __float22bfloat162_rn(t1);
        u.h[2] = __float22bfloat162_rn(t2); u.h[3] = __float22bfloat162_rn(t3);
        af[ks] = u.v;
      }

      f32x4 acc[8];
      #pragma unroll
      for (int nt = 0; nt < 8; ++nt) acc[nt] = (f32x4){0.f, 0.f, 0.f, 0.f};
      #pragma unroll
      for (int ks = 0; ks < 4; ++ks) {
        const int koff = 8 * g + 32 * ks;
        #pragma unroll
        for (int nt = 0; nt < 8; ++nt) {
          const bf16x8 bf = *reinterpret_cast<const bf16x8*>(&w1T[(16 * nt + c) * KSTR + koff]);
          acc[nt] = __builtin_amdgcn_mfma_f32_16x16x32_bf16(af[ks], bf, acc[nt], 0, 0, 0);
        }
      }

      float p[4] = {0.f, 0.f, 0.f, 0.f};
      #pragma unroll
      for (int nt = 0; nt < 8; ++nt) {
        const float b1v = b1p[16 * nt + c];
        const float w2v = w2s[16 * nt + c];
        #pragma unroll
        for (int i = 0; i < 4; ++i) {
          const float h = acc[nt][i] + b1v;
          p[i] = fmaf(gelu_fast(h), w2v, p[i]);
        }
      }
      #pragma unroll
      for (int i = 0; i < 4; ++i) {
        const int m = mbase + 4 * g + i;
        const float a = (p[i] + b2c) * notpad[m];
        s0 += a;
        sx = fmaf(a, coord_s[3 * m + 0], sx);
        sy = fmaf(a, coord_s[3 * m + 1], sy);
        sz = fmaf(a, coord_s[3 * m + 2], sz);
      }
    }

    #pragma unroll
    for (int m = 1; m <= 32; m <<= 1) {
      s0 += __shfl_xor(s0, m); sx += __shfl_xor(sx, m);
      sy += __shfl_xor(sy, m); sz += __shfl_xor(sz, m);
    }
    if (lane == 0) {
      red[row][wv4 * 4 + 0] = s0; red[row][wv4 * 4 + 1] = sx;
      red[row][wv4 * 4 + 2] = sy; red[row][wv4 * 4 + 3] = sz;
    }
  } else if (lane == 0) {
    red[row][wv4 * 4 + 0] = 0.f; red[row][wv4 * 4 + 1] = 0.f;
    red[row][wv4 * 4 + 2] = 0.f; red[row][wv4 * 4 + 3] = 0.f;
  }
  __syncthreads();

  if (ltid == 0) {
    const float cx = coord_s[3 * lrow + 0], cy = coord_s[3 * lrow + 1], cz = coord_s[3 * lrow + 2];
    float* o = outp + (bb * NL + lrow) * 3;
    if (live && (MODE == 0 ? (notpad[lrow] != 0.0f) : true)) {
      const float S0 = red[row][0] + red[row][4] + red[row][8] + red[row][12];
      const float SX = red[row][1] + red[row][5] + red[row][9] + red[row][13];
      const float SY = red[row][2] + red[row][6] + red[row][10] + red[row][14];
      const float SZ = red[row][3] + red[row][7] + red[row][11] + red[row][15];
      const float ia = invw[bb];
      o[0] = cx + (SX - S0 * cx) * ia;
      o[1] = cy + (SY - S0 * cy) * ia;
      o[2] = cz + (SZ - S0 * cz) * ia;
    } else {
      o[0] = cx; o[1] = cy; o[2] = cz;
    }
  }
}

extern "C" void kernel_launch(void* const* d_in, const int* in_sizes, int n_in,
                              void* d_out, int out_size, void* d_ws, size_t ws_size,
                              hipStream_t stream) {
  const float* x     = (const float*)d_in[0];
  const float* coord = (const float*)d_in[1];
  const int*   nodes = (const int*)d_in[2];
  const float* ln_g  = (const float*)d_in[3];
  const float* ln_b  = (const float*)d_in[4];
  const float* w1    = (const float*)d_in[5];
  const float* b1    = (const float*)d_in[6];
  const float* w2    = (const float*)d_in[7];
  const float* b2    = (const float*)d_in[8];
  float* out = (float*)d_out;

  short* w1f  = (short*)d_ws;
  float* b1p  = (float*)((char*)d_ws + 32768);
  float* npad = (float*)((char*)d_ws + 33280);
  float* inva = (float*)((char*)d_ws + 41472);

  hipLaunchKernelGGL(unimol_prep, dim3(1), dim3(256), 0, stream,
                     w1, ln_g, ln_b, b1, nodes, w1f, b1p, npad, inva);

  // ABLATION PROBE: loads+LN only, result to ws scratch (never read).
  // T_probe = dur_total - 159us tells us whether the memory stream or the
  // compute block owns the gap to the 85us HBM floor.
  if (ws_size >= (size_t)(65536 + NB * NL * 3 * 4)) {
    float* sink = (float*)((char*)d_ws + 65536);
    hipLaunchKernelGGL((unimol_coord_head<1>), dim3(NB * NL / 2), dim3(512), 0, stream,
                       x, coord, w2, b2, w1f, b1p, npad, inva, sink);
  }

  hipLaunchKernelGGL((unimol_coord_head<0>), dim3(NB * NL / 2), dim3(512), 0, stream,
                     x, coord, w2, b2, w1f, b1p, npad, inva, out);
}

// Round 10
// 194.283 us; speedup vs baseline: 1.3004x; 1.2995x over previous
//
#include <hip/hip_runtime.h>
#include <hip/hip_bf16.h>
#include <math.h>

#define NB 4
#define NL 512
#define ND 128
#define KSTR 136  // 272B row stride

typedef __attribute__((ext_vector_type(8))) short bf16x8;
typedef __attribute__((ext_vector_type(4))) float f32x4;

__device__ __forceinline__ short f2bf(float f) {
  union { float f; unsigned u; } un; un.f = f;
  unsigned r = un.u + 0x7FFFu + ((un.u >> 16) & 1u);  // RNE
  return (short)(r >> 16);
}

// GELU via sigmoid approximation: gelu(h) ~= h * sigmoid(1.702 h).
__device__ __forceinline__ float gelu_fast(float h) {
  const float e = exp2f(h * -2.4554572f);
  return h * __builtin_amdgcn_rcpf(1.0f + e);
}

__global__ void unimol_prep(const float* __restrict__ w1, const float* __restrict__ ln_g,
                            const float* __restrict__ ln_b, const float* __restrict__ b1,
                            const int* __restrict__ nodes,
                            short* __restrict__ w1f, float* __restrict__ b1p,
                            float* __restrict__ npad, float* __restrict__ inva) {
  const int tid = threadIdx.x;
  for (int idx = tid; idx < ND * ND; idx += 256) {
    const int k = idx >> 7, n = idx & (ND - 1);
    w1f[n * ND + k] = f2bf(w1[idx] * ln_g[k]);
  }
  if (tid < ND) {
    float s = b1[tid];
    for (int k = 0; k < ND; ++k) s = fmaf(ln_b[k], w1[k * ND + tid], s);
    b1p[tid] = s;
  }
  for (int j = tid; j < NB * NL; j += 256) npad[j] = (nodes[j] != 0) ? 1.0f : 0.0f;
  const int wv = tid >> 6, lane = tid & 63;
  if (wv < NB) {
    float s = 0.f;
    for (int j = lane; j < NL; j += 64) s += (nodes[wv * NL + j] != 0) ? 1.0f : 0.0f;
    #pragma unroll
    for (int m = 1; m <= 32; m <<= 1) s += __shfl_xor(s, m);
    if (lane == 0) inva[wv] = 1.0f / s;
  }
}

// 512 threads = 8 waves; waves 0-3 -> row 2*pair, waves 4-7 -> row 2*pair+1.
// Rotated loop: tile t+1's loads are issued into the SAME xv registers right
// after xv is consumed into af (its dead point), so ~900cy of HBM latency
// hides under tile t's MFMA+GELU instead of being exposed at loop top.
__global__ __launch_bounds__(512, 2) void unimol_coord_head(
    const float* __restrict__ x, const float* __restrict__ coord,
    const float* __restrict__ w2, const float* __restrict__ b2,
    const short* __restrict__ w1f, const float* __restrict__ b1pw,
    const float* __restrict__ npadw, const float* __restrict__ invw,
    float* __restrict__ out)
{
  __shared__ __align__(16) short w1T[ND * KSTR];
  __shared__ float b1p[ND];
  __shared__ float w2s[ND];
  __shared__ float notpad[NL];
  __shared__ float coord_s[NL * 3];
  __shared__ float red[2][16];

  const int blk = blockIdx.x;
  const int bb = blk >> 8;
  const int pair = blk & 255;
  const int tid = threadIdx.x;
  const int row = tid >> 8;
  const int lrow = 2 * pair + row;
  const int ltid = tid & 255;

  for (int t = tid; t < (ND * ND) / 8; t += 512) {
    const int r = t >> 4, cg = (t & 15) << 3;
    *reinterpret_cast<bf16x8*>(&w1T[r * KSTR + cg]) =
        *reinterpret_cast<const bf16x8*>(&w1f[r * ND + cg]);
  }
  if (tid < ND) { b1p[tid] = b1pw[tid]; w2s[tid] = w2[tid]; }
  for (int j = tid; j < NL; j += 512) notpad[j] = npadw[bb * NL + j];
  for (int j = tid; j < NL * 3; j += 512) coord_s[j] = coord[bb * (NL * 3) + j];
  __syncthreads();

  const int lane = tid & 63;
  const int wv4 = (tid >> 6) & 3;
  const int c = lane & 15;   // A-row within tile / D-column within tile
  const int g = lane >> 4;   // k-group
  const bool live = (notpad[lrow] != 0.0f);

  if (live) {
    float b1r[8], w2r[8];
    #pragma unroll
    for (int nt = 0; nt < 8; ++nt) { b1r[nt] = b1p[16 * nt + c]; w2r[nt] = w2s[16 * nt + c]; }
    const float b2c = b2[0] * (1.0f / 16.0f);
    float s0 = 0.f, sx = 0.f, sy = 0.f, sz = 0.f;
    const size_t xbase = (size_t)(bb * NL + lrow) * (NL * ND);

    const float* xr = x + xbase + (size_t)((wv4 << 4) + c) * ND + 8 * g;

    // prologue: tile 0 loads
    f32x4 xv[8];
    #pragma unroll
    for (int ks = 0; ks < 4; ++ks) {
      xv[2 * ks]     = *reinterpret_cast<const f32x4*>(xr + 32 * ks);
      xv[2 * ks + 1] = *reinterpret_cast<const f32x4*>(xr + 32 * ks + 4);
    }

    #pragma unroll 1
    for (int it = 0; it < 8; ++it) {
      const int mbase = (it << 6) + (wv4 << 4);
      // LayerNorm stats (waits on xv): 4 lanes (c, g=0..3) share a row
      float sum = 0.f, sq = 0.f;
      #pragma unroll
      for (int q = 0; q < 8; ++q) {
        #pragma unroll
        for (int j = 0; j < 4; ++j) { const float e = xv[q][j]; sum += e; sq = fmaf(e, e, sq); }
      }
      sum += __shfl_xor(sum, 16); sum += __shfl_xor(sum, 32);
      sq  += __shfl_xor(sq, 16);  sq  += __shfl_xor(sq, 32);
      const float mu = sum * (1.0f / ND);
      const float rs = rsqrtf(fmaf(-mu, mu, sq * (1.0f / ND)) + 1e-5f);
      const float nmr = -mu * rs;

      // xv -> af (xv dead after this point)
      bf16x8 af[4];
      #pragma unroll
      for (int ks = 0; ks < 4; ++ks) {
        union { bf16x8 v; __hip_bfloat162 h[4]; } u;
        float2 t0, t1, t2, t3;
        t0.x = fmaf(xv[2 * ks][0], rs, nmr);     t0.y = fmaf(xv[2 * ks][1], rs, nmr);
        t1.x = fmaf(xv[2 * ks][2], rs, nmr);     t1.y = fmaf(xv[2 * ks][3], rs, nmr);
        t2.x = fmaf(xv[2 * ks + 1][0], rs, nmr); t2.y = fmaf(xv[2 * ks + 1][1], rs, nmr);
        t3.x = fmaf(xv[2 * ks + 1][2], rs, nmr); t3.y = fmaf(xv[2 * ks + 1][3], rs, nmr);
        u.h[0] = __float22bfloat162_rn(t0); u.h[1] = __float22bfloat162_rn(t1);
        u.h[2] = __float22bfloat162_rn(t2); u.h[3] = __float22bfloat162_rn(t3);
        af[ks] = u.v;
      }

      // prefetch tile t+1 into the SAME xv registers (no extra VGPR);
      // latency hides under the MFMA + gelu block below
      xr += 64 * ND;
      if (it < 7) {
        #pragma unroll
        for (int ks = 0; ks < 4; ++ks) {
          xv[2 * ks]     = *reinterpret_cast<const f32x4*>(xr + 32 * ks);
          xv[2 * ks + 1] = *reinterpret_cast<const f32x4*>(xr + 32 * ks + 4);
        }
      }

      f32x4 acc[8];
      #pragma unroll
      for (int nt = 0; nt < 8; ++nt) acc[nt] = (f32x4){0.f, 0.f, 0.f, 0.f};
      #pragma unroll
      for (int ks = 0; ks < 4; ++ks) {
        const int koff = 8 * g + 32 * ks;
        #pragma unroll
        for (int nt = 0; nt < 8; ++nt) {
          const bf16x8 bf = *reinterpret_cast<const bf16x8*>(&w1T[(16 * nt + c) * KSTR + koff]);
          acc[nt] = __builtin_amdgcn_mfma_f32_16x16x32_bf16(af[ks], bf, acc[nt], 0, 0, 0);
        }
      }

      float p[4] = {0.f, 0.f, 0.f, 0.f};
      #pragma unroll
      for (int nt = 0; nt < 8; ++nt) {
        #pragma unroll
        for (int i = 0; i < 4; ++i) {
          const float h = acc[nt][i] + b1r[nt];
          p[i] = fmaf(gelu_fast(h), w2r[nt], p[i]);
        }
      }
      #pragma unroll
      for (int i = 0; i < 4; ++i) {
        const int m = mbase + 4 * g + i;
        const float a = (p[i] + b2c) * notpad[m];
        s0 += a;
        sx = fmaf(a, coord_s[3 * m + 0], sx);
        sy = fmaf(a, coord_s[3 * m + 1], sy);
        sz = fmaf(a, coord_s[3 * m + 2], sz);
      }
    }

    #pragma unroll
    for (int m = 1; m <= 32; m <<= 1) {
      s0 += __shfl_xor(s0, m); sx += __shfl_xor(sx, m);
      sy += __shfl_xor(sy, m); sz += __shfl_xor(sz, m);
    }
    if (lane == 0) {
      red[row][wv4 * 4 + 0] = s0; red[row][wv4 * 4 + 1] = sx;
      red[row][wv4 * 4 + 2] = sy; red[row][wv4 * 4 + 3] = sz;
    }
  } else if (lane == 0) {
    red[row][wv4 * 4 + 0] = 0.f; red[row][wv4 * 4 + 1] = 0.f;
    red[row][wv4 * 4 + 2] = 0.f; red[row][wv4 * 4 + 3] = 0.f;
  }
  __syncthreads();

  if (ltid == 0) {
    const float cx = coord_s[3 * lrow + 0], cy = coord_s[3 * lrow + 1], cz = coord_s[3 * lrow + 2];
    float* o = out + (bb * NL + lrow) * 3;
    if (live) {
      const float S0 = red[row][0] + red[row][4] + red[row][8] + red[row][12];
      const float SX = red[row][1] + red[row][5] + red[row][9] + red[row][13];
      const float SY = red[row][2] + red[row][6] + red[row][10] + red[row][14];
      const float SZ = red[row][3] + red[row][7] + red[row][11] + red[row][15];
      const float ia = invw[bb];
      o[0] = cx + (SX - S0 * cx) * ia;
      o[1] = cy + (SY - S0 * cy) * ia;
      o[2] = cz + (SZ - S0 * cz) * ia;
    } else {
      o[0] = cx; o[1] = cy; o[2] = cz;
    }
  }
}

extern "C" void kernel_launch(void* const* d_in, const int* in_sizes, int n_in,
                              void* d_out, int out_size, void* d_ws, size_t ws_size,
                              hipStream_t stream) {
  const float* x     = (const float*)d_in[0];
  const float* coord = (const float*)d_in[1];
  const int*   nodes = (const int*)d_in[2];
  const float* ln_g  = (const float*)d_in[3];
  const float* ln_b  = (const float*)d_in[4];
  const float* w1    = (const float*)d_in[5];
  const float* b1    = (const float*)d_in[6];
  const float* w2    = (const float*)d_in[7];
  const float* b2    = (const float*)d_in[8];
  float* out = (float*)d_out;

  short* w1f  = (short*)d_ws;
  float* b1p  = (float*)((char*)d_ws + 32768);
  float* npad = (float*)((char*)d_ws + 33280);
  float* inva = (float*)((char*)d_ws + 41472);

  hipLaunchKernelGGL(unimol_prep, dim3(1), dim3(256), 0, stream,
                     w1, ln_g, ln_b, b1, nodes, w1f, b1p, npad, inva);
  hipLaunchKernelGGL(unimol_coord_head, dim3(NB * NL / 2), dim3(512), 0, stream,
                     x, coord, w2, b2, w1f, b1p, npad, inva, out);
}

// Round 11
// 153.237 us; speedup vs baseline: 1.6487x; 1.2679x over previous
//
#include <hip/hip_runtime.h>
#include <hip/hip_bf16.h>
#include <math.h>

#define NB 4
#define NL 512
#define ND 128
#define KSTR 136  // 272B row stride

typedef __attribute__((ext_vector_type(8))) short bf16x8;
typedef __attribute__((ext_vector_type(4))) float f32x4;

__device__ __forceinline__ short f2bf(float f) {
  union { float f; unsigned u; } un; un.f = f;
  unsigned r = un.u + 0x7FFFu + ((un.u >> 16) & 1u);  // RNE
  return (short)(r >> 16);
}

// GELU via sigmoid approximation: gelu(h) ~= h * sigmoid(1.702 h).
__device__ __forceinline__ float gelu_fast(float h) {
  const float e = exp2f(h * -2.4554572f);
  return h * __builtin_amdgcn_rcpf(1.0f + e);
}

// prep: gamma-folded bf16 w1 [n][k]; beta-folded b1; column sums s1_n of the
// EXACT bf16 weights (so the post-MFMA LN correction cancels exactly);
// notpad; 1/atom_num.
__global__ void unimol_prep(const float* __restrict__ w1, const float* __restrict__ ln_g,
                            const float* __restrict__ ln_b, const float* __restrict__ b1,
                            const int* __restrict__ nodes,
                            short* __restrict__ w1f, float* __restrict__ b1p,
                            float* __restrict__ s1p,
                            float* __restrict__ npad, float* __restrict__ inva) {
  const int tid = threadIdx.x;
  for (int idx = tid; idx < ND * ND; idx += 256) {
    const int k = idx >> 7, n = idx & (ND - 1);
    w1f[n * ND + k] = f2bf(w1[idx] * ln_g[k]);
  }
  __syncthreads();
  if (tid < ND) {
    float s = b1[tid];
    for (int k = 0; k < ND; ++k) s = fmaf(ln_b[k], w1[k * ND + tid], s);
    b1p[tid] = s;
    // column sum of the bf16-rounded, gamma-folded weights
    float cs = 0.f;
    for (int k = 0; k < ND; ++k) {
      union { unsigned u; float f; } v; v.u = ((unsigned)(unsigned short)w1f[tid * ND + k]) << 16;
      cs += v.f;
    }
    s1p[tid] = cs;
  }
  for (int j = tid; j < NB * NL; j += 256) npad[j] = (nodes[j] != 0) ? 1.0f : 0.0f;
  const int wv = tid >> 6, lane = tid & 63;
  if (wv < NB) {
    float s = 0.f;
    for (int j = lane; j < NL; j += 64) s += (nodes[wv * NL + j] != 0) ? 1.0f : 0.0f;
    #pragma unroll
    for (int m = 1; m <= 32; m <<= 1) s += __shfl_xor(s, m);
    if (lane == 0) inva[wv] = 1.0f / s;
  }
}

// LN folded past the MFMA: convert RAW x to bf16 and start MFMAs immediately;
// stats (sum/sq + shfl + rsqrt) run as an independent chain the scheduler can
// overlap with the MFMA block; correction h = rs*acc + (b1 - rs*mu*s1) after.
__global__ __launch_bounds__(512, 2) void unimol_coord_head(
    const float* __restrict__ x, const float* __restrict__ coord,
    const float* __restrict__ w2, const float* __restrict__ b2,
    const short* __restrict__ w1f, const float* __restrict__ b1pw,
    const float* __restrict__ s1pw,
    const float* __restrict__ npadw, const float* __restrict__ invw,
    float* __restrict__ out)
{
  __shared__ __align__(16) short w1T[ND * KSTR];
  __shared__ float b1p[ND];
  __shared__ float w2s[ND];
  __shared__ float s1s[ND];
  __shared__ float notpad[NL];
  __shared__ float coord_s[NL * 3];
  __shared__ float red[2][16];

  const int blk = blockIdx.x;
  const int bb = blk >> 8;
  const int pair = blk & 255;
  const int tid = threadIdx.x;
  const int row = tid >> 8;
  const int lrow = 2 * pair + row;
  const int ltid = tid & 255;

  for (int t = tid; t < (ND * ND) / 8; t += 512) {
    const int r = t >> 4, cg = (t & 15) << 3;
    *reinterpret_cast<bf16x8*>(&w1T[r * KSTR + cg]) =
        *reinterpret_cast<const bf16x8*>(&w1f[r * ND + cg]);
  }
  if (tid < ND) { b1p[tid] = b1pw[tid]; w2s[tid] = w2[tid]; s1s[tid] = s1pw[tid]; }
  for (int j = tid; j < NL; j += 512) notpad[j] = npadw[bb * NL + j];
  for (int j = tid; j < NL * 3; j += 512) coord_s[j] = coord[bb * (NL * 3) + j];
  __syncthreads();

  const int lane = tid & 63;
  const int wv4 = (tid >> 6) & 3;
  const int c = lane & 15;   // A-row within tile / D-column within tile
  const int g = lane >> 4;   // k-group
  const bool live = (notpad[lrow] != 0.0f);

  if (live) {
    float b1r[8], w2r[8], s1r[8];
    #pragma unroll
    for (int nt = 0; nt < 8; ++nt) {
      b1r[nt] = b1p[16 * nt + c];
      w2r[nt] = w2s[16 * nt + c];
      s1r[nt] = s1s[16 * nt + c];
    }
    const float b2c = b2[0] * (1.0f / 16.0f);
    float s0 = 0.f, sx = 0.f, sy = 0.f, sz = 0.f;
    const size_t xbase = (size_t)(bb * NL + lrow) * (NL * ND);
    const float* xr = x + xbase + (size_t)((wv4 << 4) + c) * ND + 8 * g;

    for (int it = 0; it < 8; ++it, xr += 64 * ND) {
      const int mbase = (it << 6) + (wv4 << 4);
      f32x4 xv[8];
      #pragma unroll
      for (int ks = 0; ks < 4; ++ks) {
        xv[2 * ks]     = *reinterpret_cast<const f32x4*>(xr + 32 * ks);
        xv[2 * ks + 1] = *reinterpret_cast<const f32x4*>(xr + 32 * ks + 4);
      }

      // RAW x -> bf16 fragments (short pre-MFMA chain: just cvt_pk)
      bf16x8 af[4];
      #pragma unroll
      for (int ks = 0; ks < 4; ++ks) {
        union { bf16x8 v; __hip_bfloat162 h[4]; } u;
        float2 t0, t1, t2, t3;
        t0.x = xv[2 * ks][0];     t0.y = xv[2 * ks][1];
        t1.x = xv[2 * ks][2];     t1.y = xv[2 * ks][3];
        t2.x = xv[2 * ks + 1][0]; t2.y = xv[2 * ks + 1][1];
        t3.x = xv[2 * ks + 1][2]; t3.y = xv[2 * ks + 1][3];
        u.h[0] = __float22bfloat162_rn(t0); u.h[1] = __float22bfloat162_rn(t1);
        u.h[2] = __float22bfloat162_rn(t2); u.h[3] = __float22bfloat162_rn(t3);
        af[ks] = u.v;
      }

      // LN stats: independent of the MFMA block -> scheduler overlaps them
      float sum = 0.f, sq = 0.f;
      #pragma unroll
      for (int q = 0; q < 8; ++q) {
        #pragma unroll
        for (int j = 0; j < 4; ++j) { const float e = xv[q][j]; sum += e; sq = fmaf(e, e, sq); }
      }
      sum += __shfl_xor(sum, 16); sum += __shfl_xor(sum, 32);
      sq  += __shfl_xor(sq, 16);  sq  += __shfl_xor(sq, 32);
      const float mu = sum * (1.0f / ND);
      const float rs = rsqrtf(fmaf(-mu, mu, sq * (1.0f / ND)) + 1e-5f);
      const float nrsmu = -rs * mu;

      f32x4 acc[8];
      #pragma unroll
      for (int nt = 0; nt < 8; ++nt) acc[nt] = (f32x4){0.f, 0.f, 0.f, 0.f};
      #pragma unroll
      for (int ks = 0; ks < 4; ++ks) {
        const int koff = 8 * g + 32 * ks;
        #pragma unroll
        for (int nt = 0; nt < 8; ++nt) {
          const bf16x8 bf = *reinterpret_cast<const bf16x8*>(&w1T[(16 * nt + c) * KSTR + koff]);
          acc[nt] = __builtin_amdgcn_mfma_f32_16x16x32_bf16(af[ks], bf, acc[nt], 0, 0, 0);
        }
      }

      // post-MFMA LN correction + GELU + w2 dot
      float p[4] = {0.f, 0.f, 0.f, 0.f};
      #pragma unroll
      for (int nt = 0; nt < 8; ++nt) {
        const float tmp = fmaf(s1r[nt], nrsmu, b1r[nt]);  // b1 - rs*mu*s1_n
        #pragma unroll
        for (int i = 0; i < 4; ++i) {
          const float h = fmaf(acc[nt][i], rs, tmp);
          p[i] = fmaf(gelu_fast(h), w2r[nt], p[i]);
        }
      }
      #pragma unroll
      for (int i = 0; i < 4; ++i) {
        const int m = mbase + 4 * g + i;
        const float a = (p[i] + b2c) * notpad[m];
        s0 += a;
        sx = fmaf(a, coord_s[3 * m + 0], sx);
        sy = fmaf(a, coord_s[3 * m + 1], sy);
        sz = fmaf(a, coord_s[3 * m + 2], sz);
      }
    }

    #pragma unroll
    for (int m = 1; m <= 32; m <<= 1) {
      s0 += __shfl_xor(s0, m); sx += __shfl_xor(sx, m);
      sy += __shfl_xor(sy, m); sz += __shfl_xor(sz, m);
    }
    if (lane == 0) {
      red[row][wv4 * 4 + 0] = s0; red[row][wv4 * 4 + 1] = sx;
      red[row][wv4 * 4 + 2] = sy; red[row][wv4 * 4 + 3] = sz;
    }
  } else if (lane == 0) {
    red[row][wv4 * 4 + 0] = 0.f; red[row][wv4 * 4 + 1] = 0.f;
    red[row][wv4 * 4 + 2] = 0.f; red[row][wv4 * 4 + 3] = 0.f;
  }
  __syncthreads();

  if (ltid == 0) {
    const float cx = coord_s[3 * lrow + 0], cy = coord_s[3 * lrow + 1], cz = coord_s[3 * lrow + 2];
    float* o = out + (bb * NL + lrow) * 3;
    if (live) {
      const float S0 = red[row][0] + red[row][4] + red[row][8] + red[row][12];
      const float SX = red[row][1] + red[row][5] + red[row][9] + red[row][13];
      const float SY = red[row][2] + red[row][6] + red[row][10] + red[row][14];
      const float SZ = red[row][3] + red[row][7] + red[row][11] + red[row][15];
      const float ia = invw[bb];
      o[0] = cx + (SX - S0 * cx) * ia;
      o[1] = cy + (SY - S0 * cy) * ia;
      o[2] = cz + (SZ - S0 * cz) * ia;
    } else {
      o[0] = cx; o[1] = cy; o[2] = cz;
    }
  }
}

extern "C" void kernel_launch(void* const* d_in, const int* in_sizes, int n_in,
                              void* d_out, int out_size, void* d_ws, size_t ws_size,
                              hipStream_t stream) {
  const float* x     = (const float*)d_in[0];
  const float* coord = (const float*)d_in[1];
  const int*   nodes = (const int*)d_in[2];
  const float* ln_g  = (const float*)d_in[3];
  const float* ln_b  = (const float*)d_in[4];
  const float* w1    = (const float*)d_in[5];
  const float* b1    = (const float*)d_in[6];
  const float* w2    = (const float*)d_in[7];
  const float* b2    = (const float*)d_in[8];
  float* out = (float*)d_out;

  short* w1f  = (short*)d_ws;                       // 32768 B
  float* b1p  = (float*)((char*)d_ws + 32768);      // 512 B
  float* s1p  = (float*)((char*)d_ws + 33280);      // 512 B
  float* npad = (float*)((char*)d_ws + 33792);      // 8192 B
  float* inva = (float*)((char*)d_ws + 41984);      // 16 B

  hipLaunchKernelGGL(unimol_prep, dim3(1), dim3(256), 0, stream,
                     w1, ln_g, ln_b, b1, nodes, w1f, b1p, s1p, npad, inva);
  hipLaunchKernelGGL(unimol_coord_head, dim3(NB * NL / 2), dim3(512), 0, stream,
                     x, coord, w2, b2, w1f, b1p, s1p, npad, inva, out);
}